// Round 7
// baseline (1690.657 us; speedup 1.0000x reference)
//
#include <hip/hip_runtime.h>
#include <hip/hip_cooperative_groups.h>

namespace cg = cooperative_groups;

#define D 512
#define T 50000
#define K 16
#define NIT 10

#define NBLK 256            // PROVEN coop-resident grid: 1 block/CU.
#define BTH  1024           // 16 waves/CU (was 8): the BW lever. VGPR must be <=128.
#define COLS_PER_BLOCK 196  // 256*196 = 50176 >= 50000
#define GRP2 98             // two-col groups per block
#define PASSES 2            // 2 passes x 64 groups covers 98

// ---- one-shot tree barrier geometry ----
#define NLEAF 16
#define BLK_PER_LEAF (NBLK / NLEAF)   // 16
#define BAR_PAD 32                    // u64 per counter slot = 256B line padding

#define LAMBDA1 0.3366f
#define LR      0.1f
#define SHRINK_C (LR * LAMBDA1)
#define BETA1   0.9f
#define BETA2   0.999f
#define ADAM_EPS 1e-8f

__device__ __forceinline__ float sgn(float x) {
    return (x > 0.f) ? 1.f : ((x < 0.f) ? -1.f : 0.f);
}

// residual FMA + abs-accumulate for one row, 2 columns per lane.
// Per-column arithmetic identical (values and order) to the R2 float4 body.
__device__ __forceinline__ void accum_row2(const float2 e, const float* __restrict__ brow,
                                           const float2* __restrict__ a2, float2& acc) {
    float bb[K];
    *reinterpret_cast<float4*>(&bb[0])  = reinterpret_cast<const float4*>(brow)[0];
    *reinterpret_cast<float4*>(&bb[4])  = reinterpret_cast<const float4*>(brow)[1];
    *reinterpret_cast<float4*>(&bb[8])  = reinterpret_cast<const float4*>(brow)[2];
    *reinterpret_cast<float4*>(&bb[12]) = reinterpret_cast<const float4*>(brow)[3];
    float2 r = e;
#pragma unroll
    for (int k = 0; k < K; ++k) {
        r.x = fmaf(-bb[k], a2[k].x, r.x);
        r.y = fmaf(-bb[k], a2[k].y, r.y);
    }
    acc.x += fabsf(r.x); acc.y += fabsf(r.y);
}

// One-shot 2-level tree barrier (tid==0 of each block, fresh counters per
// iteration -> no reset/generation races). ~7us/iter cheaper than grid.sync.
__device__ __forceinline__ void bar_arrive_wait(unsigned long long* __restrict__ bar,
                                                int it0, int bid) {
    unsigned long long* leaf = &bar[(size_t)((it0 * NLEAF) + (bid & (NLEAF - 1))) * BAR_PAD];
    unsigned long long* root = &bar[(size_t)((NIT * NLEAF) + it0) * BAR_PAD];
    __threadfence();   // my slot atomicMax is globally visible before arrival
    if (atomicAdd(leaf, 1ull) == (unsigned long long)(BLK_PER_LEAF - 1)) {
        __threadfence();
        atomicAdd(root, 1ull);
    }
    long long guard = 0;
    while (__hip_atomic_load(root, __ATOMIC_RELAXED, __HIP_MEMORY_SCOPE_AGENT)
           < (unsigned long long)NLEAF) {
        __builtin_amdgcn_s_sleep(2);
        if (++guard > (1ll << 26)) break;   // safety: never hang the container
    }
    __threadfence();   // acquire: later reads see all pre-barrier writes
}

// Persistent cooperative kernel, 1024 threads/block (16 waves/CU).
// Phase 1: lane owns 2 columns (a2 in regs), slice of 32 rows; B from LDS.
// Update: threads 0..511 (thread = row), state P/m/v in registers.
// Cross-block comm is ONLY argmax slots + barrier counters (device-scope
// atomics); every block redoes the update on bitwise-identical local state.
__global__ __launch_bounds__(BTH) void diar_all(
        const float* __restrict__ E, const float* __restrict__ Bin,
        const float* __restrict__ A, float* __restrict__ out,
        unsigned long long* __restrict__ slot, unsigned long long* __restrict__ bar) {
    __shared__ __align__(16) float Bl[D * K];      // 32 KB, current B
    __shared__ float2 psum[16][64];                // 8 KB per-slice col partials
    __shared__ float wsum[8][K];                   // per-wave |B| col partials
    __shared__ float colA[K];
    __shared__ int js_s, ks_s;

    const int tid = threadIdx.x;
    const int bid = blockIdx.x;
    cg::grid_group grid = cg::this_grid();

    // ---- init block-local state: thread tid (<512) owns row tid ----
    float pr[K], mr[K], vr[K];
    if (tid < D) {
        const float4* src = reinterpret_cast<const float4*>(Bin + tid * K);
        float4* bl4 = reinterpret_cast<float4*>(&Bl[tid * K]);
#pragma unroll
        for (int q = 0; q < 4; ++q) {
            float4 x = src[q];
            bl4[q] = x;
            pr[4 * q + 0] = x.x; pr[4 * q + 1] = x.y;
            pr[4 * q + 2] = x.z; pr[4 * q + 3] = x.w;
        }
#pragma unroll
        for (int k = 0; k < K; ++k) { mr[k] = 0.f; vr[k] = 0.f; }
    }
    // zero argmax slots + ALL barrier counters (ws poisoned 0xAA each call).
    if (bid == 0) {
        const int nbar = (NIT * NLEAF + NIT) * BAR_PAD;   // 5440 u64
        for (int q = tid; q < nbar; q += BTH) bar[q] = 0ull;
        if (tid < NIT) slot[tid] = 0ull;
        __threadfence();
    }
    __syncthreads();
    grid.sync();   // ONE cg sync: zeroed counters visible device-wide

    const int c = tid & 63;          // 2-col group lane within pass
    const int s = tid >> 6;          // row slice (0..15, 32 rows each)

    float b1p = 1.f, b2p = 1.f;

    for (int it = 1; it <= NIT; ++it) {
        b1p *= BETA1; b2p *= BETA2;

        // ---- phase 1: residual column abs-sums, 2 passes of 64 groups ----
        unsigned long long key = 0ull;   // accumulated in lanes tid<64
#pragma unroll
        for (int p = 0; p < PASSES; ++p) {
            const int g = p * 64 + c;
            const int j0 = bid * COLS_PER_BLOCK + g * 2;
            const bool ok = (g < GRP2);
            float2 acc = {0.f, 0.f};
            if (ok) {
                float2 a2[K];
#pragma unroll
                for (int k = 0; k < K; ++k)
                    a2[k] = *reinterpret_cast<const float2*>(A + (size_t)k * T + j0);
                const int rbase = s * 32;
                const float* Ep = E + j0;
                float2 eb[4];
#pragma unroll
                for (int ch = 0; ch < 8; ++ch) {
#pragma unroll
                    for (int u = 0; u < 4; ++u)
                        eb[u] = *reinterpret_cast<const float2*>(
                            Ep + (size_t)(rbase + ch * 4 + u) * T);
#pragma unroll
                    for (int u = 0; u < 4; ++u)
                        accum_row2(eb[u], &Bl[(rbase + ch * 4 + u) * K], a2, acc);
                }
            }
            psum[s][c] = acc;
            __syncthreads();
            if (tid < 64) {
                const int gg = p * 64 + tid;
                if (gg < GRP2) {
                    float2 cs = psum[0][tid];
#pragma unroll
                    for (int q = 1; q < 16; ++q) {   // fixed order -> deterministic
                        float2 pq = psum[q][tid];
                        cs.x += pq.x; cs.y += pq.y;
                    }
                    const int jb = bid * COLS_PER_BLOCK + gg * 2;
                    float v2[2] = {cs.x, cs.y};
#pragma unroll
                    for (int q = 0; q < 2; ++q) {
                        unsigned long long kq =
                            (((unsigned long long)__float_as_uint(v2[q])) << 32)
                            | (unsigned int)(jb + q);
                        if (kq > key) key = kq;     // ties -> largest j
                    }
                }
            }
            __syncthreads();   // psum reused next pass
        }
        if (tid < 64) {   // wave 0 merge
#pragma unroll
            for (int off = 32; off > 0; off >>= 1) {
                unsigned long long o = __shfl_down(key, off, 64);
                if (o > key) key = o;
            }
            if (tid == 0) atomicMax(&slot[it - 1], key);
        }

        // ---- cross-block barrier + argmax pickup (thread 0 only) ----
        if (tid == 0) {
            bar_arrive_wait(bar, it - 1, bid);
            unsigned long long kk = atomicMax(&slot[it - 1], 0ull);  // coherent read
            js_s = (int)(kk & 0xffffffffull);
        }
        __syncthreads();
        const int js = js_s;
        if (tid < K) colA[tid] = A[(size_t)tid * T + js];

        // B column L1 norms: waves 0-7 (threads <512), fixed-order merge
        if (tid < D) {
            const float* brow = &Bl[tid * K];
            float cb[K];
#pragma unroll
            for (int k = 0; k < K; ++k) cb[k] = fabsf(brow[k]);
#pragma unroll
            for (int off = 32; off > 0; off >>= 1) {
#pragma unroll
                for (int k = 0; k < K; ++k) cb[k] += __shfl_down(cb[k], off, 64);
            }
            if ((tid & 63) == 0) {
                const int w = tid >> 6;   // 0..7
#pragma unroll
                for (int k = 0; k < K; ++k) wsum[w][k] = cb[k];
            }
        }
        __syncthreads();
        if (tid == 0) {
            float best = -1.f; int kb = 0;
#pragma unroll
            for (int k = 0; k < K; ++k) {
                float t = 0.f;
                for (int w = 0; w < 8; ++w) t += wsum[w][k];   // fixed order
                if (t > best) { best = t; kb = k; }            // first-max
            }
            ks_s = kb;
        }
        __syncthreads();
        const int ks = ks_s;
        const float biasm = 1.f - b1p;
        const float biasv = 1.f - b2p;

        if (tid < D) {
            // residual sign for my row at column j*
            float r = E[(size_t)tid * T + js];
            const float* brow = &Bl[tid * K];
#pragma unroll
            for (int k = 0; k < K; ++k) r = fmaf(-brow[k], colA[k], r);
            const float sg = sgn(r);

            // Adam step on P (registers), then B = shrink(P) back to LDS
#pragma unroll
            for (int k = 0; k < K; ++k) {
                float g = -sg * colA[k];
                if (k == ks) g += LAMBDA1 * sgn(brow[k]);
                float p = pr[k];
                if (it >= 2) g *= sgn(p) * sgn(p - SHRINK_C);   // d shrink/dp a.e.
                float mm = BETA1 * mr[k] + (1.f - BETA1) * g;
                float vv = BETA2 * vr[k] + (1.f - BETA2) * g * g;
                mr[k] = mm; vr[k] = vv;
                p -= LR * (mm / biasm) / (sqrtf(vv / biasv) + ADAM_EPS);
                pr[k] = p;
            }
            float4* bl4 = reinterpret_cast<float4*>(&Bl[tid * K]);
#pragma unroll
            for (int q = 0; q < 4; ++q) {
                float4 x;
                x.x = sgn(pr[4 * q + 0]) * fmaxf(0.f, fabsf(pr[4 * q + 0] - SHRINK_C));
                x.y = sgn(pr[4 * q + 1]) * fmaxf(0.f, fabsf(pr[4 * q + 1] - SHRINK_C));
                x.z = sgn(pr[4 * q + 2]) * fmaxf(0.f, fabsf(pr[4 * q + 2] - SHRINK_C));
                x.w = sgn(pr[4 * q + 3]) * fmaxf(0.f, fabsf(pr[4 * q + 3] - SHRINK_C));
                bl4[q] = x;
            }
        }
        __syncthreads();   // Bl updated before next iteration's phase 1
    }

    // ---- output: [shrink(P) (8192) | A (800000)] ----
    if (bid == 0 && tid < D) {
        float4* o4 = reinterpret_cast<float4*>(out);
        const float4* b4 = reinterpret_cast<const float4*>(Bl);
#pragma unroll
        for (int q = 0; q < 4; ++q) o4[tid * 4 + q] = b4[tid * 4 + q];
    }
    {
        float4* o4 = reinterpret_cast<float4*>(out) + (D * K) / 4;
        const float4* a4p = reinterpret_cast<const float4*>(A);
        const int n4 = (K * T) / 4;   // 200000
        for (int q = bid * BTH + tid; q < n4; q += NBLK * BTH) o4[q] = a4p[q];
    }
}

extern "C" void kernel_launch(void* const* d_in, const int* in_sizes, int n_in,
                              void* d_out, int out_size, void* d_ws, size_t ws_size,
                              hipStream_t stream) {
    const float* E   = (const float*)d_in[0];   // (D, T)
    const float* Bin = (const float*)d_in[1];   // (D, K)
    const float* A   = (const float*)d_in[2];   // (K, T)
    float* out = (float*)d_out;
    unsigned long long* slot = (unsigned long long*)d_ws;          // NIT slots
    unsigned long long* bar  = (unsigned long long*)((char*)d_ws + 1024); // ~43.5 KB

    void* args[] = { (void*)&E, (void*)&Bin, (void*)&A, (void*)&out,
                     (void*)&slot, (void*)&bar };
    hipLaunchCooperativeKernel((void*)diar_all, dim3(NBLK), dim3(BTH),
                               args, 0, stream);
}

// Round 8
// 1686.691 us; speedup vs baseline: 1.0024x; 1.0024x over previous
//
#include <hip/hip_runtime.h>
#include <hip/hip_cooperative_groups.h>

namespace cg = cooperative_groups;

#define D 512
#define T 50000
#define K 16
#define NIT 10

#define NBLK 256            // PROVEN coop-resident grid: 1 block/CU.
#define BTH  1024           // 16 waves/CU. launch_bounds(1024,4) => VGPR cap 128.
#define COLS_PER_BLOCK 196  // 256*196 = 50176 >= 50000
#define GRP2 98             // two-col groups per block
#define PASSES 2            // 2 passes x 64 groups covers 98

// ---- one-shot tree barrier geometry ----
#define NLEAF 16
#define BLK_PER_LEAF (NBLK / NLEAF)   // 16
#define BAR_PAD 32                    // u64 per counter slot = 256B line padding

#define LAMBDA1 0.3366f
#define LR      0.1f
#define SHRINK_C (LR * LAMBDA1)
#define BETA1   0.9f
#define BETA2   0.999f
#define ADAM_EPS 1e-8f

__device__ __forceinline__ float sgn(float x) {
    return (x > 0.f) ? 1.f : ((x < 0.f) ? -1.f : 0.f);
}

// residual FMA + abs-accumulate for one row, 2 columns per lane.
// Per-column arithmetic identical (values and order) to the R2 float4 body.
__device__ __forceinline__ void accum_row2(const float2 e, const float* __restrict__ brow,
                                           const float2* __restrict__ a2, float2& acc) {
    float bb[K];
    *reinterpret_cast<float4*>(&bb[0])  = reinterpret_cast<const float4*>(brow)[0];
    *reinterpret_cast<float4*>(&bb[4])  = reinterpret_cast<const float4*>(brow)[1];
    *reinterpret_cast<float4*>(&bb[8])  = reinterpret_cast<const float4*>(brow)[2];
    *reinterpret_cast<float4*>(&bb[12]) = reinterpret_cast<const float4*>(brow)[3];
    float2 r = e;
#pragma unroll
    for (int k = 0; k < K; ++k) {
        r.x = fmaf(-bb[k], a2[k].x, r.x);
        r.y = fmaf(-bb[k], a2[k].y, r.y);
    }
    acc.x += fabsf(r.x); acc.y += fabsf(r.y);
}

// One-shot 2-level tree barrier (tid==0 of each block, fresh counters per
// iteration -> no reset/generation races). ~7us/iter cheaper than grid.sync.
__device__ __forceinline__ void bar_arrive_wait(unsigned long long* __restrict__ bar,
                                                int it0, int bid) {
    unsigned long long* leaf = &bar[(size_t)((it0 * NLEAF) + (bid & (NLEAF - 1))) * BAR_PAD];
    unsigned long long* root = &bar[(size_t)((NIT * NLEAF) + it0) * BAR_PAD];
    __threadfence();   // my slot atomicMax is globally visible before arrival
    if (atomicAdd(leaf, 1ull) == (unsigned long long)(BLK_PER_LEAF - 1)) {
        __threadfence();
        atomicAdd(root, 1ull);
    }
    long long guard = 0;
    while (__hip_atomic_load(root, __ATOMIC_RELAXED, __HIP_MEMORY_SCOPE_AGENT)
           < (unsigned long long)NLEAF) {
        __builtin_amdgcn_s_sleep(2);
        if (++guard > (1ll << 26)) break;   // safety: never hang the container
    }
    __threadfence();   // acquire: later reads see all pre-barrier writes
}

// Persistent cooperative kernel, 1024 threads/block (16 waves/CU).
// Phase 1: lane owns 2 columns (a2 in regs), slice of 32 rows; B from LDS.
// Update: threads 0..511 (thread = row), state P/m/v in registers.
// Cross-block comm is ONLY argmax slots + barrier counters (device-scope
// atomics); every block redoes the update on bitwise-identical local state.
__global__ __launch_bounds__(BTH, 4) void diar_all(
        const float* __restrict__ E, const float* __restrict__ Bin,
        const float* __restrict__ A, float* __restrict__ out,
        unsigned long long* __restrict__ slot, unsigned long long* __restrict__ bar) {
    __shared__ __align__(16) float Bl[D * K];      // 32 KB, current B
    __shared__ float2 psum[16][64];                // 8 KB per-slice col partials
    __shared__ float wsum[8][K];                   // per-wave |B| col partials
    __shared__ float colA[K];
    __shared__ int js_s, ks_s;

    const int tid = threadIdx.x;
    const int bid = blockIdx.x;
    cg::grid_group grid = cg::this_grid();

    // ---- init block-local state: thread tid (<512) owns row tid ----
    float pr[K], mr[K], vr[K];
    if (tid < D) {
        const float4* src = reinterpret_cast<const float4*>(Bin + tid * K);
        float4* bl4 = reinterpret_cast<float4*>(&Bl[tid * K]);
#pragma unroll
        for (int q = 0; q < 4; ++q) {
            float4 x = src[q];
            bl4[q] = x;
            pr[4 * q + 0] = x.x; pr[4 * q + 1] = x.y;
            pr[4 * q + 2] = x.z; pr[4 * q + 3] = x.w;
        }
#pragma unroll
        for (int k = 0; k < K; ++k) { mr[k] = 0.f; vr[k] = 0.f; }
    }
    // zero argmax slots + ALL barrier counters (ws poisoned 0xAA each call).
    if (bid == 0) {
        const int nbar = (NIT * NLEAF + NIT) * BAR_PAD;   // 5440 u64
        for (int q = tid; q < nbar; q += BTH) bar[q] = 0ull;
        if (tid < NIT) slot[tid] = 0ull;
        __threadfence();
    }
    __syncthreads();
    grid.sync();   // ONE cg sync: zeroed counters visible device-wide

    const int c = tid & 63;          // 2-col group lane within pass
    const int s = tid >> 6;          // row slice (0..15, 32 rows each)

    float b1p = 1.f, b2p = 1.f;

    for (int it = 1; it <= NIT; ++it) {
        b1p *= BETA1; b2p *= BETA2;

        // ---- phase 1: residual column abs-sums, 2 passes of 64 groups ----
        unsigned long long key = 0ull;   // accumulated in lanes tid<64
#pragma unroll
        for (int p = 0; p < PASSES; ++p) {
            const int g = p * 64 + c;
            const int j0 = bid * COLS_PER_BLOCK + g * 2;
            const bool ok = (g < GRP2);
            float2 acc = {0.f, 0.f};
            if (ok) {
                float2 a2[K];
#pragma unroll
                for (int k = 0; k < K; ++k)
                    a2[k] = *reinterpret_cast<const float2*>(A + (size_t)k * T + j0);
                const int rbase = s * 32;
                const float* Ep = E + j0;
                float2 eb[4];
#pragma unroll
                for (int ch = 0; ch < 8; ++ch) {
#pragma unroll
                    for (int u = 0; u < 4; ++u)
                        eb[u] = *reinterpret_cast<const float2*>(
                            Ep + (size_t)(rbase + ch * 4 + u) * T);
#pragma unroll
                    for (int u = 0; u < 4; ++u)
                        accum_row2(eb[u], &Bl[(rbase + ch * 4 + u) * K], a2, acc);
                }
            }
            psum[s][c] = acc;
            __syncthreads();
            if (tid < 64) {
                const int gg = p * 64 + tid;
                if (gg < GRP2) {
                    float2 cs = psum[0][tid];
#pragma unroll
                    for (int q = 1; q < 16; ++q) {   // fixed order -> deterministic
                        float2 pq = psum[q][tid];
                        cs.x += pq.x; cs.y += pq.y;
                    }
                    const int jb = bid * COLS_PER_BLOCK + gg * 2;
                    float v2[2] = {cs.x, cs.y};
#pragma unroll
                    for (int q = 0; q < 2; ++q) {
                        unsigned long long kq =
                            (((unsigned long long)__float_as_uint(v2[q])) << 32)
                            | (unsigned int)(jb + q);
                        if (kq > key) key = kq;     // ties -> largest j
                    }
                }
            }
            __syncthreads();   // psum reused next pass
        }
        if (tid < 64) {   // wave 0 merge
#pragma unroll
            for (int off = 32; off > 0; off >>= 1) {
                unsigned long long o = __shfl_down(key, off, 64);
                if (o > key) key = o;
            }
            if (tid == 0) atomicMax(&slot[it - 1], key);
        }

        // ---- cross-block barrier + argmax pickup (thread 0 only) ----
        if (tid == 0) {
            bar_arrive_wait(bar, it - 1, bid);
            unsigned long long kk = atomicMax(&slot[it - 1], 0ull);  // coherent read
            js_s = (int)(kk & 0xffffffffull);
        }
        __syncthreads();
        const int js = js_s;
        if (tid < K) colA[tid] = A[(size_t)tid * T + js];

        // B column L1 norms: waves 0-7 (threads <512), fixed-order merge
        if (tid < D) {
            const float* brow = &Bl[tid * K];
            float cb[K];
#pragma unroll
            for (int k = 0; k < K; ++k) cb[k] = fabsf(brow[k]);
#pragma unroll
            for (int off = 32; off > 0; off >>= 1) {
#pragma unroll
                for (int k = 0; k < K; ++k) cb[k] += __shfl_down(cb[k], off, 64);
            }
            if ((tid & 63) == 0) {
                const int w = tid >> 6;   // 0..7
#pragma unroll
                for (int k = 0; k < K; ++k) wsum[w][k] = cb[k];
            }
        }
        __syncthreads();
        if (tid == 0) {
            float best = -1.f; int kb = 0;
#pragma unroll
            for (int k = 0; k < K; ++k) {
                float t = 0.f;
                for (int w = 0; w < 8; ++w) t += wsum[w][k];   // fixed order
                if (t > best) { best = t; kb = k; }            // first-max
            }
            ks_s = kb;
        }
        __syncthreads();
        const int ks = ks_s;
        const float biasm = 1.f - b1p;
        const float biasv = 1.f - b2p;

        if (tid < D) {
            // residual sign for my row at column j*
            float r = E[(size_t)tid * T + js];
            const float* brow = &Bl[tid * K];
#pragma unroll
            for (int k = 0; k < K; ++k) r = fmaf(-brow[k], colA[k], r);
            const float sg = sgn(r);

            // Adam step on P (registers), then B = shrink(P) back to LDS
#pragma unroll
            for (int k = 0; k < K; ++k) {
                float g = -sg * colA[k];
                if (k == ks) g += LAMBDA1 * sgn(brow[k]);
                float p = pr[k];
                if (it >= 2) g *= sgn(p) * sgn(p - SHRINK_C);   // d shrink/dp a.e.
                float mm = BETA1 * mr[k] + (1.f - BETA1) * g;
                float vv = BETA2 * vr[k] + (1.f - BETA2) * g * g;
                mr[k] = mm; vr[k] = vv;
                p -= LR * (mm / biasm) / (sqrtf(vv / biasv) + ADAM_EPS);
                pr[k] = p;
            }
            float4* bl4 = reinterpret_cast<float4*>(&Bl[tid * K]);
#pragma unroll
            for (int q = 0; q < 4; ++q) {
                float4 x;
                x.x = sgn(pr[4 * q + 0]) * fmaxf(0.f, fabsf(pr[4 * q + 0] - SHRINK_C));
                x.y = sgn(pr[4 * q + 1]) * fmaxf(0.f, fabsf(pr[4 * q + 1] - SHRINK_C));
                x.z = sgn(pr[4 * q + 2]) * fmaxf(0.f, fabsf(pr[4 * q + 2] - SHRINK_C));
                x.w = sgn(pr[4 * q + 3]) * fmaxf(0.f, fabsf(pr[4 * q + 3] - SHRINK_C));
                bl4[q] = x;
            }
        }
        __syncthreads();   // Bl updated before next iteration's phase 1
    }

    // ---- output: [shrink(P) (8192) | A (800000)] ----
    if (bid == 0 && tid < D) {
        float4* o4 = reinterpret_cast<float4*>(out);
        const float4* b4 = reinterpret_cast<const float4*>(Bl);
#pragma unroll
        for (int q = 0; q < 4; ++q) o4[tid * 4 + q] = b4[tid * 4 + q];
    }
    {
        float4* o4 = reinterpret_cast<float4*>(out) + (D * K) / 4;
        const float4* a4p = reinterpret_cast<const float4*>(A);
        const int n4 = (K * T) / 4;   // 200000
        for (int q = bid * BTH + tid; q < n4; q += NBLK * BTH) o4[q] = a4p[q];
    }
}

extern "C" void kernel_launch(void* const* d_in, const int* in_sizes, int n_in,
                              void* d_out, int out_size, void* d_ws, size_t ws_size,
                              hipStream_t stream) {
    const float* E   = (const float*)d_in[0];   // (D, T)
    const float* Bin = (const float*)d_in[1];   // (D, K)
    const float* A   = (const float*)d_in[2];   // (K, T)
    float* out = (float*)d_out;
    unsigned long long* slot = (unsigned long long*)d_ws;          // NIT slots
    unsigned long long* bar  = (unsigned long long*)((char*)d_ws + 1024); // ~43.5 KB

    void* args[] = { (void*)&E, (void*)&Bin, (void*)&A, (void*)&out,
                     (void*)&slot, (void*)&bar };
    hipLaunchCooperativeKernel((void*)diar_all, dim3(NBLK), dim3(BTH),
                               args, 0, stream);
}

// Round 9
// 780.552 us; speedup vs baseline: 2.1660x; 2.1609x over previous
//
#include <hip/hip_runtime.h>
#include <hip/hip_cooperative_groups.h>

namespace cg = cooperative_groups;

#define D 512
#define T 50000
#define K 16
#define NIT 10

#define NBLK 256            // PROVEN coop-resident grid: 1 block/CU.
#define BTH  1024           // 16 waves/CU. waves_per_eu(4,4) => VGPR budget 128.
#define COLS_PER_BLOCK 196  // 256*196 = 50176 >= 50000
#define GRP2 98             // two-col groups per block
#define PASSES 2            // 2 passes x 64 groups covers 98

// ---- one-shot tree barrier geometry ----
#define NLEAF 16
#define BLK_PER_LEAF (NBLK / NLEAF)   // 16
#define BAR_PAD 32                    // u64 per counter slot = 256B line padding

#define LAMBDA1 0.3366f
#define LR      0.1f
#define SHRINK_C (LR * LAMBDA1)
#define BETA1   0.9f
#define BETA2   0.999f
#define ADAM_EPS 1e-8f

__device__ __forceinline__ float sgn(float x) {
    return (x > 0.f) ? 1.f : ((x < 0.f) ? -1.f : 0.f);
}

// residual FMA + abs-accumulate for one row, 2 columns per lane.
// Per-column arithmetic identical (values and order) to the R2 float4 body.
__device__ __forceinline__ void accum_row2(const float2 e, const float* __restrict__ brow,
                                           const float2* __restrict__ a2, float2& acc) {
    float bb[K];
    *reinterpret_cast<float4*>(&bb[0])  = reinterpret_cast<const float4*>(brow)[0];
    *reinterpret_cast<float4*>(&bb[4])  = reinterpret_cast<const float4*>(brow)[1];
    *reinterpret_cast<float4*>(&bb[8])  = reinterpret_cast<const float4*>(brow)[2];
    *reinterpret_cast<float4*>(&bb[12]) = reinterpret_cast<const float4*>(brow)[3];
    float2 r = e;
#pragma unroll
    for (int k = 0; k < K; ++k) {
        r.x = fmaf(-bb[k], a2[k].x, r.x);
        r.y = fmaf(-bb[k], a2[k].y, r.y);
    }
    acc.x += fabsf(r.x); acc.y += fabsf(r.y);
}

// One-shot 2-level tree barrier (tid==0 of each block, fresh counters per
// iteration -> no reset/generation races). ~7us/iter cheaper than grid.sync.
__device__ __forceinline__ void bar_arrive_wait(unsigned long long* __restrict__ bar,
                                                int it0, int bid) {
    unsigned long long* leaf = &bar[(size_t)((it0 * NLEAF) + (bid & (NLEAF - 1))) * BAR_PAD];
    unsigned long long* root = &bar[(size_t)((NIT * NLEAF) + it0) * BAR_PAD];
    __threadfence();   // my slot atomicMax is globally visible before arrival
    if (atomicAdd(leaf, 1ull) == (unsigned long long)(BLK_PER_LEAF - 1)) {
        __threadfence();
        atomicAdd(root, 1ull);
    }
    long long guard = 0;
    while (__hip_atomic_load(root, __ATOMIC_RELAXED, __HIP_MEMORY_SCOPE_AGENT)
           < (unsigned long long)NLEAF) {
        __builtin_amdgcn_s_sleep(2);
        if (++guard > (1ll << 26)) break;   // safety: never hang the container
    }
    __threadfence();   // acquire: later reads see all pre-barrier writes
}

// Persistent cooperative kernel, 1024 threads/block (16 waves/CU).
// amdgpu_waves_per_eu(4,4): pin exactly 4 waves/EU so the register
// allocator uses the full 128-VGPR budget instead of spilling to hit an
// 8-waves/EU occupancy the 42KB LDS makes impossible (R7/R8: 2x0.94GB
// scratch traffic, VGPR_Count=64).
__global__ __launch_bounds__(BTH)
__attribute__((amdgpu_waves_per_eu(4, 4))) void diar_all(
        const float* __restrict__ E, const float* __restrict__ Bin,
        const float* __restrict__ A, float* __restrict__ out,
        unsigned long long* __restrict__ slot, unsigned long long* __restrict__ bar) {
    __shared__ __align__(16) float Bl[D * K];      // 32 KB, current B
    __shared__ float2 psum[16][64];                // 8 KB per-slice col partials
    __shared__ float wsum[8][K];                   // per-wave |B| col partials
    __shared__ float colA[K];
    __shared__ int js_s, ks_s;

    const int tid = threadIdx.x;
    const int bid = blockIdx.x;
    cg::grid_group grid = cg::this_grid();

    // ---- init block-local state: thread tid (<512) owns row tid ----
    float pr[K], mr[K], vr[K];
    if (tid < D) {
        const float4* src = reinterpret_cast<const float4*>(Bin + tid * K);
        float4* bl4 = reinterpret_cast<float4*>(&Bl[tid * K]);
#pragma unroll
        for (int q = 0; q < 4; ++q) {
            float4 x = src[q];
            bl4[q] = x;
            pr[4 * q + 0] = x.x; pr[4 * q + 1] = x.y;
            pr[4 * q + 2] = x.z; pr[4 * q + 3] = x.w;
        }
#pragma unroll
        for (int k = 0; k < K; ++k) { mr[k] = 0.f; vr[k] = 0.f; }
    }
    // zero argmax slots + ALL barrier counters (ws poisoned 0xAA each call).
    if (bid == 0) {
        const int nbar = (NIT * NLEAF + NIT) * BAR_PAD;   // 5440 u64
        for (int q = tid; q < nbar; q += BTH) bar[q] = 0ull;
        if (tid < NIT) slot[tid] = 0ull;
        __threadfence();
    }
    __syncthreads();
    grid.sync();   // ONE cg sync: zeroed counters visible device-wide

    const int c = tid & 63;          // 2-col group lane within pass
    const int s = tid >> 6;          // row slice (0..15, 32 rows each)

    float b1p = 1.f, b2p = 1.f;

    for (int it = 1; it <= NIT; ++it) {
        b1p *= BETA1; b2p *= BETA2;

        // ---- phase 1: residual column abs-sums, 2 passes of 64 groups ----
        unsigned long long key = 0ull;   // accumulated in lanes tid<64
#pragma unroll
        for (int p = 0; p < PASSES; ++p) {
            const int g = p * 64 + c;
            const int j0 = bid * COLS_PER_BLOCK + g * 2;
            const bool ok = (g < GRP2);
            float2 acc = {0.f, 0.f};
            if (ok) {
                float2 a2[K];
#pragma unroll
                for (int k = 0; k < K; ++k)
                    a2[k] = *reinterpret_cast<const float2*>(A + (size_t)k * T + j0);
                const int rbase = s * 32;
                const float* Ep = E + j0;
#pragma unroll 8
                for (int ii = 0; ii < 32; ++ii) {
                    const int i = rbase + ii;
                    const float2 e = *reinterpret_cast<const float2*>(Ep + (size_t)i * T);
                    accum_row2(e, &Bl[i * K], a2, acc);
                }
            }
            psum[s][c] = acc;
            __syncthreads();
            if (tid < 64) {
                const int gg = p * 64 + tid;
                if (gg < GRP2) {
                    float2 cs = psum[0][tid];
#pragma unroll
                    for (int q = 1; q < 16; ++q) {   // fixed order -> deterministic
                        float2 pq = psum[q][tid];
                        cs.x += pq.x; cs.y += pq.y;
                    }
                    const int jb = bid * COLS_PER_BLOCK + gg * 2;
                    float v2[2] = {cs.x, cs.y};
#pragma unroll
                    for (int q = 0; q < 2; ++q) {
                        unsigned long long kq =
                            (((unsigned long long)__float_as_uint(v2[q])) << 32)
                            | (unsigned int)(jb + q);
                        if (kq > key) key = kq;     // ties -> largest j
                    }
                }
            }
            __syncthreads();   // psum reused next pass
        }
        if (tid < 64) {   // wave 0 merge
#pragma unroll
            for (int off = 32; off > 0; off >>= 1) {
                unsigned long long o = __shfl_down(key, off, 64);
                if (o > key) key = o;
            }
            if (tid == 0) atomicMax(&slot[it - 1], key);
        }

        // ---- cross-block barrier + argmax pickup (thread 0 only) ----
        if (tid == 0) {
            bar_arrive_wait(bar, it - 1, bid);
            unsigned long long kk = atomicMax(&slot[it - 1], 0ull);  // coherent read
            js_s = (int)(kk & 0xffffffffull);
        }
        __syncthreads();
        const int js = js_s;
        if (tid < K) colA[tid] = A[(size_t)tid * T + js];

        // B column L1 norms: waves 0-7 (threads <512), fixed-order merge
        if (tid < D) {
            const float* brow = &Bl[tid * K];
            float cb[K];
#pragma unroll
            for (int k = 0; k < K; ++k) cb[k] = fabsf(brow[k]);
#pragma unroll
            for (int off = 32; off > 0; off >>= 1) {
#pragma unroll
                for (int k = 0; k < K; ++k) cb[k] += __shfl_down(cb[k], off, 64);
            }
            if ((tid & 63) == 0) {
                const int w = tid >> 6;   // 0..7
#pragma unroll
                for (int k = 0; k < K; ++k) wsum[w][k] = cb[k];
            }
        }
        __syncthreads();
        if (tid == 0) {
            float best = -1.f; int kb = 0;
#pragma unroll
            for (int k = 0; k < K; ++k) {
                float t = 0.f;
                for (int w = 0; w < 8; ++w) t += wsum[w][k];   // fixed order
                if (t > best) { best = t; kb = k; }            // first-max
            }
            ks_s = kb;
        }
        __syncthreads();
        const int ks = ks_s;
        const float biasm = 1.f - b1p;
        const float biasv = 1.f - b2p;

        if (tid < D) {
            // residual sign for my row at column j*
            float r = E[(size_t)tid * T + js];
            const float* brow = &Bl[tid * K];
#pragma unroll
            for (int k = 0; k < K; ++k) r = fmaf(-brow[k], colA[k], r);
            const float sg = sgn(r);

            // Adam step on P (registers), then B = shrink(P) back to LDS
#pragma unroll
            for (int k = 0; k < K; ++k) {
                float g = -sg * colA[k];
                if (k == ks) g += LAMBDA1 * sgn(brow[k]);
                float p = pr[k];
                if (it >= 2) g *= sgn(p) * sgn(p - SHRINK_C);   // d shrink/dp a.e.
                float mm = BETA1 * mr[k] + (1.f - BETA1) * g;
                float vv = BETA2 * vr[k] + (1.f - BETA2) * g * g;
                mr[k] = mm; vr[k] = vv;
                p -= LR * (mm / biasm) / (sqrtf(vv / biasv) + ADAM_EPS);
                pr[k] = p;
            }
            float4* bl4 = reinterpret_cast<float4*>(&Bl[tid * K]);
#pragma unroll
            for (int q = 0; q < 4; ++q) {
                float4 x;
                x.x = sgn(pr[4 * q + 0]) * fmaxf(0.f, fabsf(pr[4 * q + 0] - SHRINK_C));
                x.y = sgn(pr[4 * q + 1]) * fmaxf(0.f, fabsf(pr[4 * q + 1] - SHRINK_C));
                x.z = sgn(pr[4 * q + 2]) * fmaxf(0.f, fabsf(pr[4 * q + 2] - SHRINK_C));
                x.w = sgn(pr[4 * q + 3]) * fmaxf(0.f, fabsf(pr[4 * q + 3] - SHRINK_C));
                bl4[q] = x;
            }
        }
        __syncthreads();   // Bl updated before next iteration's phase 1
    }

    // ---- output: [shrink(P) (8192) | A (800000)] ----
    if (bid == 0 && tid < D) {
        float4* o4 = reinterpret_cast<float4*>(out);
        const float4* b4 = reinterpret_cast<const float4*>(Bl);
#pragma unroll
        for (int q = 0; q < 4; ++q) o4[tid * 4 + q] = b4[tid * 4 + q];
    }
    {
        float4* o4 = reinterpret_cast<float4*>(out) + (D * K) / 4;
        const float4* a4p = reinterpret_cast<const float4*>(A);
        const int n4 = (K * T) / 4;   // 200000
        for (int q = bid * BTH + tid; q < n4; q += NBLK * BTH) o4[q] = a4p[q];
    }
}

extern "C" void kernel_launch(void* const* d_in, const int* in_sizes, int n_in,
                              void* d_out, int out_size, void* d_ws, size_t ws_size,
                              hipStream_t stream) {
    const float* E   = (const float*)d_in[0];   // (D, T)
    const float* Bin = (const float*)d_in[1];   // (D, K)
    const float* A   = (const float*)d_in[2];   // (K, T)
    float* out = (float*)d_out;
    unsigned long long* slot = (unsigned long long*)d_ws;          // NIT slots
    unsigned long long* bar  = (unsigned long long*)((char*)d_ws + 1024); // ~43.5 KB

    void* args[] = { (void*)&E, (void*)&Bin, (void*)&A, (void*)&out,
                     (void*)&slot, (void*)&bar };
    hipLaunchCooperativeKernel((void*)diar_all, dim3(NBLK), dim3(BTH),
                               args, 0, stream);
}